// Round 5
// baseline (163.877 us; speedup 1.0000x reference)
//
#include <hip/hip_runtime.h>
#include <math.h>

#define DD 4096
#define EE 64
#define BK 32
#define TAU 1e-4f
#define NEG_SENTINEL -1.0e30f
#define MAXFIX 16000

typedef __attribute__((ext_vector_type(8))) short short8v;
typedef __attribute__((ext_vector_type(4))) float f32x4;

union BF8 {
  uint4 u;
  short8v s;
};

__device__ __forceinline__ unsigned asu(float f) {
  union { float f; unsigned u; } v; v.f = f; return v.u;
}
__device__ __forceinline__ float asf(unsigned u) {
  union { unsigned u; float f; } v; v.u = u; return v.f;
}

// Split 8 f32 into hi/lo bf16 (RNE both): x = hi + lo + O(2^-17 |x|).
__device__ __forceinline__ void split8(const float x[8], uint4& hi, uint4& lo) {
  unsigned h[8], l[8];
#pragma unroll
  for (int j = 0; j < 8; j++) {
    unsigned u = asu(x[j]);
    unsigned r = (u + 0x7fffu + ((u >> 16) & 1u)) & 0xffff0000u;
    h[j] = r;
    unsigned v = asu(x[j] - asf(r));
    l[j] = (v + 0x7fffu + ((v >> 16) & 1u)) & 0xffff0000u;
  }
  hi = make_uint4((h[0] >> 16) | h[1], (h[2] >> 16) | h[3],
                  (h[4] >> 16) | h[5], (h[6] >> 16) | h[7]);
  lo = make_uint4((l[0] >> 16) | l[1], (l[2] >> 16) | l[3],
                  (l[4] >> 16) | l[5], (l[6] >> 16) | l[7]);
}

// ---------------------------------------------------------------------------
// Kernel 1: bf16-split MFMA partial GEMM, A direct-to-register (no A LDS).
// Block: 128 rows x 64 experts, 4 waves (wave = 32 rows: mt 2 x nt 4 tiles of
// 16x16x32). A frag loaded per-lane from global (layout verified by R4 pass),
// split to hi/lo bf16 in-register. LDS holds B only: per step 64e x 32k as
// hi/lo planes (4KB each), double-buffered (16KB total).
// B LDS swizzle: line = e>>1 (128B), sub = (((e&1)<<2)|slot) ^ (line&7):
// both write (64 lanes = 64 distinct slots) and read (8 lines x 8 subs) are
// exactly 8-deep = the 1KB/wave LDS minimum -> conflict-free.
// Barrier = lgkmcnt(0) + raw s_barrier (no vmcnt drain: global prefetch is
// wave-local). A/B prefetched one K-step ahead in registers.
// ---------------------------------------------------------------------------
template <int KSPLIT>
__global__ __launch_bounds__(256, 2) void gemm_mfma(
    const float* __restrict__ hidden, const float* __restrict__ gate_w,
    float* __restrict__ part, int nrows) {
  __shared__ __align__(16) char smem[16384];

  const int tid = threadIdx.x;
  const int lane = tid & 63;
  const int wv = tid >> 6;
  const int fr = lane & 15;
  const int fg = lane >> 4;
  const int m0 = blockIdx.x * 128;
  const int kslice = DD / KSPLIT;
  const int nsteps = kslice / BK;
  const int k0 = blockIdx.y * kslice;

  // A: wave wv owns rows m0+32wv .. +31; lane reads 8 floats per mt tile.
  const float* pA0 = hidden + (size_t)(m0 + wv * 32 + fr) * DD + k0 + fg * 8;
  const float* pA1 = pA0 + (size_t)16 * DD;
  // B staging: thread -> (expert, k-octet)
  const int be = tid & 63;
  const int bs = tid >> 6;
  const float* pB = gate_w + (size_t)be * DD + k0 + bs * 8;
  const int wline = be >> 1;
  const int woff = wline * 128 + ((((be & 1) << 2) | bs) ^ (wline & 7)) * 16;
  // B frag-read base for this lane (nt adds +1024, lo plane +4096)
  const int rbase =
      (fr >> 1) * 128 + ((((fr & 1) << 2) | fg) ^ ((fr >> 1) & 7)) * 16;

  float4 ac[2][2], an[2][2], bn[2];

  auto stageB = [&](int nb) {
    float xb[8] = {bn[0].x, bn[0].y, bn[0].z, bn[0].w,
                   bn[1].x, bn[1].y, bn[1].z, bn[1].w};
    uint4 hi, lo;
    split8(xb, hi, lo);
    *(uint4*)(smem + nb + woff) = hi;
    *(uint4*)(smem + nb + 4096 + woff) = lo;
  };

  // ---- prologue: load t=0, stage B0, prefetch t=1 ----
  ac[0][0] = *(const float4*)pA0;
  ac[0][1] = *(const float4*)(pA0 + 4);
  ac[1][0] = *(const float4*)pA1;
  ac[1][1] = *(const float4*)(pA1 + 4);
  bn[0] = *(const float4*)pB;
  bn[1] = *(const float4*)(pB + 4);
  pA0 += BK; pA1 += BK; pB += BK;
  stageB(0);
  an[0][0] = *(const float4*)pA0;
  an[0][1] = *(const float4*)(pA0 + 4);
  an[1][0] = *(const float4*)pA1;
  an[1][1] = *(const float4*)(pA1 + 4);
  bn[0] = *(const float4*)pB;
  bn[1] = *(const float4*)(pB + 4);
  pA0 += BK; pA1 += BK; pB += BK;
  asm volatile("s_waitcnt lgkmcnt(0)" ::: "memory");
  __builtin_amdgcn_s_barrier();
  asm volatile("" ::: "memory");

  f32x4 zero4 = {0.f, 0.f, 0.f, 0.f};
  f32x4 acc[2][4];
#pragma unroll
  for (int mt = 0; mt < 2; mt++)
#pragma unroll
    for (int nt = 0; nt < 4; nt++) acc[mt][nt] = zero4;

  for (int t = 0; t < nsteps; t++) {
    const int cb = (t & 1) << 13;
    // A frags (hi/lo) from current regs
    BF8 ah[2], al[2];
#pragma unroll
    for (int mt = 0; mt < 2; mt++) {
      float xa[8] = {ac[mt][0].x, ac[mt][0].y, ac[mt][0].z, ac[mt][0].w,
                     ac[mt][1].x, ac[mt][1].y, ac[mt][1].z, ac[mt][1].w};
      split8(xa, ah[mt].u, al[mt].u);
    }
    // stage B(t+1) into the other buffer (prev readers drained by barrier)
    if (t + 1 < nsteps) stageB(cb ^ 8192);
    // roll A regs; issue prefetch for t+2
#pragma unroll
    for (int mt = 0; mt < 2; mt++) {
      ac[mt][0] = an[mt][0];
      ac[mt][1] = an[mt][1];
    }
    if (t + 2 < nsteps) {
      an[0][0] = *(const float4*)pA0;
      an[0][1] = *(const float4*)(pA0 + 4);
      an[1][0] = *(const float4*)pA1;
      an[1][1] = *(const float4*)(pA1 + 4);
      bn[0] = *(const float4*)pB;
      bn[1] = *(const float4*)(pB + 4);
      pA0 += BK; pA1 += BK; pB += BK;
    }
    // B frags from LDS + 24 MFMAs (3-pass bf16-split)
#pragma unroll
    for (int nt = 0; nt < 4; nt++) {
      BF8 bh, bl;
      bh.u = *(const uint4*)(smem + cb + rbase + nt * 1024);
      bl.u = *(const uint4*)(smem + cb + 4096 + rbase + nt * 1024);
#pragma unroll
      for (int mt = 0; mt < 2; mt++) {
        acc[mt][nt] = __builtin_amdgcn_mfma_f32_16x16x32_bf16(
            ah[mt].s, bh.s, acc[mt][nt], 0, 0, 0);
        acc[mt][nt] = __builtin_amdgcn_mfma_f32_16x16x32_bf16(
            ah[mt].s, bl.s, acc[mt][nt], 0, 0, 0);
        acc[mt][nt] = __builtin_amdgcn_mfma_f32_16x16x32_bf16(
            al[mt].s, bh.s, acc[mt][nt], 0, 0, 0);
      }
    }
    asm volatile("s_waitcnt lgkmcnt(0)" ::: "memory");
    __builtin_amdgcn_s_barrier();
    asm volatile("" ::: "memory");
  }

  // partial logits: part[ks][row][e]; C/D: row=(l>>4)*4+j, col=l&15
  float* dst = part + (size_t)blockIdx.y * nrows * EE;
#pragma unroll
  for (int mt = 0; mt < 2; mt++)
#pragma unroll
    for (int j = 0; j < 4; j++) {
      const int r = m0 + wv * 32 + mt * 16 + fg * 4 + j;
#pragma unroll
      for (int nt = 0; nt < 4; nt++)
        dst[(size_t)r * EE + nt * 16 + fr] = acc[mt][nt][j];
    }
}

// ---------------------------------------------------------------------------
// Kernel 2: reduce partials, sqrt(softplus), top-8 (lax.top_k tie-break),
// renormalize, scatter. Flags rows with selection margin < TAU for exact
// f32 recompute (bf16-split logit error <= ~2e-5, TAU gives 15x headroom).
// ---------------------------------------------------------------------------
__global__ __launch_bounds__(256) void topk_kernel(
    const float* __restrict__ part, const float* __restrict__ bias,
    float* __restrict__ out, int nrows, int ksplit, int* __restrict__ counter,
    int* __restrict__ list) {
  const int lane = threadIdx.x & 63;
  const int row = blockIdx.x * 4 + (threadIdx.x >> 6);

  float logit = 0.0f;
  for (int s = 0; s < ksplit; s++)
    logit += part[(size_t)s * nrows * EE + (size_t)row * EE + lane];

  float sp = (logit > 0.0f) ? (logit + log1pf(expf(-logit)))
                            : log1pf(expf(logit));
  float score = sqrtf(sp);
  float sel = score + bias[lane];

  float denom = 0.0f, v8 = 0.0f;
  bool chosen = false;
#pragma unroll
  for (int t = 0; t < 8; t++) {
    float v = sel;
    int idx = lane;
#pragma unroll
    for (int m = 1; m < 64; m <<= 1) {
      float ov = __shfl_xor(v, m, 64);
      int oi = __shfl_xor(idx, m, 64);
      if (ov > v || (ov == v && oi < idx)) { v = ov; idx = oi; }
    }
    float wscore = __shfl(score, idx, 64);
    denom += wscore;
    v8 = v;
    if (lane == idx) { chosen = true; sel = NEG_SENTINEL; }
  }
  // 9th-best for selection margin
  float v9 = sel;
#pragma unroll
  for (int m = 1; m < 64; m <<= 1) v9 = fmaxf(v9, __shfl_xor(v9, m, 64));
  if (lane == 0 && (v8 - v9) < TAU) {
    int ix = atomicAdd(counter, 1);
    if (ix < MAXFIX) list[ix] = row;
  }

  denom = fmaxf(denom, 1e-12f);
  out[(size_t)row * EE + lane] = chosen ? (score / denom) : 0.0f;
  out[(size_t)nrows * EE + (size_t)row * EE + lane] = chosen ? 1.0f : 0.0f;
}

// ---------------------------------------------------------------------------
// Kernel 3: exact-f32 recompute of flagged rows (few).
// ---------------------------------------------------------------------------
__global__ __launch_bounds__(256) void fixup_kernel(
    const float* __restrict__ hidden, const float* __restrict__ gate_w,
    const float* __restrict__ bias, const int* __restrict__ counter,
    const int* __restrict__ list, float* __restrict__ out, int nrows) {
  __shared__ float red[EE][4];
  int cnt = *counter;
  if (cnt > MAXFIX) cnt = MAXFIX;
  for (int i = blockIdx.x; i < cnt; i += gridDim.x) {
    const int row = list[i];
    const int e = threadIdx.x & 63;
    const int q = threadIdx.x >> 6;
    const float* hp = hidden + (size_t)row * DD + q * 1024;
    const float* wp = gate_w + (size_t)e * DD + q * 1024;
    float s = 0.f;
    for (int k = 0; k < 1024; k += 4) {
      float4 a = *(const float4*)(hp + k);
      float4 b = *(const float4*)(wp + k);
      s = fmaf(a.w, b.w, fmaf(a.z, b.z, fmaf(a.y, b.y, fmaf(a.x, b.x, s))));
    }
    red[e][q] = s;
    __syncthreads();
    if (threadIdx.x < 64) {
      const int lane = threadIdx.x;
      float logit = red[lane][0] + red[lane][1] + red[lane][2] + red[lane][3];
      float sp = (logit > 0.0f) ? (logit + log1pf(expf(-logit)))
                                : log1pf(expf(logit));
      float score = sqrtf(sp);
      float sel = score + bias[lane];
      float denom = 0.0f;
      bool chosen = false;
#pragma unroll
      for (int t = 0; t < 8; t++) {
        float v = sel;
        int idx = lane;
#pragma unroll
        for (int m = 1; m < 64; m <<= 1) {
          float ov = __shfl_xor(v, m, 64);
          int oi = __shfl_xor(idx, m, 64);
          if (ov > v || (ov == v && oi < idx)) { v = ov; idx = oi; }
        }
        float wscore = __shfl(score, idx, 64);
        denom += wscore;
        if (lane == idx) { chosen = true; sel = NEG_SENTINEL; }
      }
      denom = fmaxf(denom, 1e-12f);
      out[(size_t)row * EE + lane] = chosen ? (score / denom) : 0.0f;
      out[(size_t)nrows * EE + (size_t)row * EE + lane] = chosen ? 1.0f : 0.0f;
    }
    __syncthreads();
  }
}

// ---------------------------------------------------------------------------
extern "C" void kernel_launch(void* const* d_in, const int* in_sizes, int n_in,
                              void* d_out, int out_size, void* d_ws,
                              size_t ws_size, hipStream_t stream) {
  const float* hidden = (const float*)d_in[0];
  const float* gate_w = (const float*)d_in[1];
  const float* bias = (const float*)d_in[2];
  float* out = (float*)d_out;
  char* ws = (char*)d_ws;

  const int nrows = in_sizes[0] / DD;  // 16384

  size_t tail = (ws_size - 65536) & ~(size_t)255;
  int* counter = (int*)(ws + tail);
  int* list = counter + 1;
  float* part = (float*)ws;
  const size_t per = (size_t)nrows * EE * sizeof(float);  // 4 MiB
  const int ksplit = (tail >= 4 * per) ? 4 : 2;

  hipMemsetAsync(counter, 0, sizeof(int), stream);

  dim3 block(256);
  if (ksplit == 4)
    gemm_mfma<4><<<dim3(nrows / 128, 4), block, 0, stream>>>(hidden, gate_w,
                                                             part, nrows);
  else
    gemm_mfma<2><<<dim3(nrows / 128, 2), block, 0, stream>>>(hidden, gate_w,
                                                             part, nrows);
  topk_kernel<<<dim3(nrows / 4), block, 0, stream>>>(part, bias, out, nrows,
                                                     ksplit, counter, list);
  fixup_kernel<<<dim3(128), block, 0, stream>>>(hidden, gate_w, bias, counter,
                                                list, out, nrows);
}

// Round 6
// 139.709 us; speedup vs baseline: 1.1730x; 1.1730x over previous
//
#include <hip/hip_runtime.h>
#include <math.h>

#define DD 4096
#define EE 64
#define BK 32
#define TAU 1e-4f
#define NEG_SENTINEL -1.0e30f
#define MAXFIX 16000

typedef __attribute__((ext_vector_type(8))) short short8v;
typedef __attribute__((ext_vector_type(4))) float f32x4;

union BF8 {
  uint4 u;
  short8v s;
};

__device__ __forceinline__ unsigned asu(float f) {
  union { float f; unsigned u; } v; v.f = f; return v.u;
}
__device__ __forceinline__ float asf(unsigned u) {
  union { unsigned u; float f; } v; v.u = u; return v.f;
}

// Split 8 f32 into hi/lo bf16 (RNE both): x = hi + lo + O(2^-17 |x|).
__device__ __forceinline__ void split8(const float x[8], uint4& hi, uint4& lo) {
  unsigned h[8], l[8];
#pragma unroll
  for (int j = 0; j < 8; j++) {
    unsigned u = asu(x[j]);
    unsigned r = (u + 0x7fffu + ((u >> 16) & 1u)) & 0xffff0000u;
    h[j] = r;
    unsigned v = asu(x[j] - asf(r));
    l[j] = (v + 0x7fffu + ((v >> 16) & 1u)) & 0xffff0000u;
  }
  hi = make_uint4((h[0] >> 16) | h[1], (h[2] >> 16) | h[3],
                  (h[4] >> 16) | h[5], (h[6] >> 16) | h[7]);
  lo = make_uint4((l[0] >> 16) | l[1], (l[2] >> 16) | l[3],
                  (l[4] >> 16) | l[5], (l[6] >> 16) | l[7]);
}

// ---------------------------------------------------------------------------
// Kernel 1: bf16-split MFMA partial GEMM, A direct-to-register (no A LDS).
// UNCHANGED from R5 (passing; kept fixed this round for clean attribution).
// ---------------------------------------------------------------------------
template <int KSPLIT>
__global__ __launch_bounds__(256, 2) void gemm_mfma(
    const float* __restrict__ hidden, const float* __restrict__ gate_w,
    float* __restrict__ part, int nrows) {
  __shared__ __align__(16) char smem[16384];

  const int tid = threadIdx.x;
  const int lane = tid & 63;
  const int wv = tid >> 6;
  const int fr = lane & 15;
  const int fg = lane >> 4;
  const int m0 = blockIdx.x * 128;
  const int kslice = DD / KSPLIT;
  const int nsteps = kslice / BK;
  const int k0 = blockIdx.y * kslice;

  const float* pA0 = hidden + (size_t)(m0 + wv * 32 + fr) * DD + k0 + fg * 8;
  const float* pA1 = pA0 + (size_t)16 * DD;
  const int be = tid & 63;
  const int bs = tid >> 6;
  const float* pB = gate_w + (size_t)be * DD + k0 + bs * 8;
  const int wline = be >> 1;
  const int woff = wline * 128 + ((((be & 1) << 2) | bs) ^ (wline & 7)) * 16;
  const int rbase =
      (fr >> 1) * 128 + ((((fr & 1) << 2) | fg) ^ ((fr >> 1) & 7)) * 16;

  float4 ac[2][2], an[2][2], bn[2];

  auto stageB = [&](int nb) {
    float xb[8] = {bn[0].x, bn[0].y, bn[0].z, bn[0].w,
                   bn[1].x, bn[1].y, bn[1].z, bn[1].w};
    uint4 hi, lo;
    split8(xb, hi, lo);
    *(uint4*)(smem + nb + woff) = hi;
    *(uint4*)(smem + nb + 4096 + woff) = lo;
  };

  ac[0][0] = *(const float4*)pA0;
  ac[0][1] = *(const float4*)(pA0 + 4);
  ac[1][0] = *(const float4*)pA1;
  ac[1][1] = *(const float4*)(pA1 + 4);
  bn[0] = *(const float4*)pB;
  bn[1] = *(const float4*)(pB + 4);
  pA0 += BK; pA1 += BK; pB += BK;
  stageB(0);
  an[0][0] = *(const float4*)pA0;
  an[0][1] = *(const float4*)(pA0 + 4);
  an[1][0] = *(const float4*)pA1;
  an[1][1] = *(const float4*)(pA1 + 4);
  bn[0] = *(const float4*)pB;
  bn[1] = *(const float4*)(pB + 4);
  pA0 += BK; pA1 += BK; pB += BK;
  asm volatile("s_waitcnt lgkmcnt(0)" ::: "memory");
  __builtin_amdgcn_s_barrier();
  asm volatile("" ::: "memory");

  f32x4 zero4 = {0.f, 0.f, 0.f, 0.f};
  f32x4 acc[2][4];
#pragma unroll
  for (int mt = 0; mt < 2; mt++)
#pragma unroll
    for (int nt = 0; nt < 4; nt++) acc[mt][nt] = zero4;

  for (int t = 0; t < nsteps; t++) {
    const int cb = (t & 1) << 13;
    BF8 ah[2], al[2];
#pragma unroll
    for (int mt = 0; mt < 2; mt++) {
      float xa[8] = {ac[mt][0].x, ac[mt][0].y, ac[mt][0].z, ac[mt][0].w,
                     ac[mt][1].x, ac[mt][1].y, ac[mt][1].z, ac[mt][1].w};
      split8(xa, ah[mt].u, al[mt].u);
    }
    if (t + 1 < nsteps) stageB(cb ^ 8192);
#pragma unroll
    for (int mt = 0; mt < 2; mt++) {
      ac[mt][0] = an[mt][0];
      ac[mt][1] = an[mt][1];
    }
    if (t + 2 < nsteps) {
      an[0][0] = *(const float4*)pA0;
      an[0][1] = *(const float4*)(pA0 + 4);
      an[1][0] = *(const float4*)pA1;
      an[1][1] = *(const float4*)(pA1 + 4);
      bn[0] = *(const float4*)pB;
      bn[1] = *(const float4*)(pB + 4);
      pA0 += BK; pA1 += BK; pB += BK;
    }
#pragma unroll
    for (int nt = 0; nt < 4; nt++) {
      BF8 bh, bl;
      bh.u = *(const uint4*)(smem + cb + rbase + nt * 1024);
      bl.u = *(const uint4*)(smem + cb + 4096 + rbase + nt * 1024);
#pragma unroll
      for (int mt = 0; mt < 2; mt++) {
        acc[mt][nt] = __builtin_amdgcn_mfma_f32_16x16x32_bf16(
            ah[mt].s, bh.s, acc[mt][nt], 0, 0, 0);
        acc[mt][nt] = __builtin_amdgcn_mfma_f32_16x16x32_bf16(
            ah[mt].s, bl.s, acc[mt][nt], 0, 0, 0);
        acc[mt][nt] = __builtin_amdgcn_mfma_f32_16x16x32_bf16(
            al[mt].s, bh.s, acc[mt][nt], 0, 0, 0);
      }
    }
    asm volatile("s_waitcnt lgkmcnt(0)" ::: "memory");
    __builtin_amdgcn_s_barrier();
    asm volatile("" ::: "memory");
  }

  float* dst = part + (size_t)blockIdx.y * nrows * EE;
#pragma unroll
  for (int mt = 0; mt < 2; mt++)
#pragma unroll
    for (int j = 0; j < 4; j++) {
      const int r = m0 + wv * 32 + mt * 16 + fg * 4 + j;
#pragma unroll
      for (int nt = 0; nt < 4; nt++)
        dst[(size_t)r * EE + nt * 16 + fr] = acc[mt][nt][j];
    }
}

// ---------------------------------------------------------------------------
// Kernel 2: reduce partials, sqrt(softplus), top-8, renormalize, scatter.
// Flags rows with selection margin < TAU for exact f32 recompute.
// ---------------------------------------------------------------------------
__global__ __launch_bounds__(256) void topk_kernel(
    const float* __restrict__ part, const float* __restrict__ bias,
    float* __restrict__ out, int nrows, int ksplit, int* __restrict__ counter,
    int* __restrict__ list) {
  const int lane = threadIdx.x & 63;
  const int row = blockIdx.x * 4 + (threadIdx.x >> 6);

  float logit = 0.0f;
  for (int s = 0; s < ksplit; s++)
    logit += part[(size_t)s * nrows * EE + (size_t)row * EE + lane];

  float sp = (logit > 0.0f) ? (logit + log1pf(expf(-logit)))
                            : log1pf(expf(logit));
  float score = sqrtf(sp);
  float sel = score + bias[lane];

  float denom = 0.0f, v8 = 0.0f;
  bool chosen = false;
#pragma unroll
  for (int t = 0; t < 8; t++) {
    float v = sel;
    int idx = lane;
#pragma unroll
    for (int m = 1; m < 64; m <<= 1) {
      float ov = __shfl_xor(v, m, 64);
      int oi = __shfl_xor(idx, m, 64);
      if (ov > v || (ov == v && oi < idx)) { v = ov; idx = oi; }
    }
    float wscore = __shfl(score, idx, 64);
    denom += wscore;
    v8 = v;
    if (lane == idx) { chosen = true; sel = NEG_SENTINEL; }
  }
  float v9 = sel;
#pragma unroll
  for (int m = 1; m < 64; m <<= 1) v9 = fmaxf(v9, __shfl_xor(v9, m, 64));
  if (lane == 0 && (v8 - v9) < TAU) {
    int ix = atomicAdd(counter, 1);
    if (ix < MAXFIX) list[ix] = row;
  }

  denom = fmaxf(denom, 1e-12f);
  out[(size_t)row * EE + lane] = chosen ? (score / denom) : 0.0f;
  out[(size_t)nrows * EE + (size_t)row * EE + lane] = chosen ? 1.0f : 0.0f;
}

// ---------------------------------------------------------------------------
// Kernel 3a: exact-f32 partial dots for flagged rows, k-split 16 ways.
// Work item w = (row-slot i, k-chunk c of 256 floats); grid-stride.
// Block: 256 thr, thread (e = tid&63, q = tid>>6) dots 64 floats.
// part2[i][e][c] written deterministically (no data atomics).
// ---------------------------------------------------------------------------
__global__ __launch_bounds__(256) void fixup_partial(
    const float* __restrict__ hidden, const float* __restrict__ gate_w,
    const int* __restrict__ counter, const int* __restrict__ list,
    float* __restrict__ part2) {
  __shared__ float red[EE][4];
  int cnt = *counter;
  if (cnt > MAXFIX) cnt = MAXFIX;
  const int total = cnt * 16;
  const int e = threadIdx.x & 63;
  const int q = threadIdx.x >> 6;
  for (int w = blockIdx.x; w < total; w += gridDim.x) {
    const int i = w >> 4;
    const int c = w & 15;
    const int row = list[i];
    const int kb = c * 256 + q * 64;
    const float* hp = hidden + (size_t)row * DD + kb;
    const float* wp = gate_w + (size_t)e * DD + kb;
    float s = 0.f;
#pragma unroll
    for (int k = 0; k < 64; k += 4) {
      float4 a = *(const float4*)(hp + k);
      float4 b = *(const float4*)(wp + k);
      s = fmaf(a.w, b.w, fmaf(a.z, b.z, fmaf(a.y, b.y, fmaf(a.x, b.x, s))));
    }
    red[e][q] = s;
    __syncthreads();
    if (threadIdx.x < EE)
      part2[(size_t)i * 1024 + threadIdx.x * 16 + c] =
          (red[threadIdx.x][0] + red[threadIdx.x][1]) +
          (red[threadIdx.x][2] + red[threadIdx.x][3]);
    __syncthreads();
  }
}

// ---------------------------------------------------------------------------
// Kernel 3b: sum the 16 chunks in fixed order, redo top-8 exactly, rewrite.
// One wave per flagged row; 4 waves/block; grid-stride.
// ---------------------------------------------------------------------------
__global__ __launch_bounds__(256) void fixup_apply(
    const float* __restrict__ part2, const float* __restrict__ bias,
    const int* __restrict__ counter, const int* __restrict__ list,
    float* __restrict__ out, int nrows) {
  int cnt = *counter;
  if (cnt > MAXFIX) cnt = MAXFIX;
  const int lane = threadIdx.x & 63;
  const int wv = threadIdx.x >> 6;
  for (int i0 = blockIdx.x * 4; i0 < cnt; i0 += gridDim.x * 4) {
    const int i = i0 + wv;
    if (i >= cnt) continue;
    const int row = list[i];
    const float* pp = part2 + (size_t)i * 1024 + lane * 16;
    float logit = 0.f;
#pragma unroll
    for (int c = 0; c < 16; c++) logit += pp[c];

    float sp = (logit > 0.0f) ? (logit + log1pf(expf(-logit)))
                              : log1pf(expf(logit));
    float score = sqrtf(sp);
    float sel = score + bias[lane];
    float denom = 0.0f;
    bool chosen = false;
#pragma unroll
    for (int t = 0; t < 8; t++) {
      float v = sel;
      int idx = lane;
#pragma unroll
      for (int m = 1; m < 64; m <<= 1) {
        float ov = __shfl_xor(v, m, 64);
        int oi = __shfl_xor(idx, m, 64);
        if (ov > v || (ov == v && oi < idx)) { v = ov; idx = oi; }
      }
      float wscore = __shfl(score, idx, 64);
      denom += wscore;
      if (lane == idx) { chosen = true; sel = NEG_SENTINEL; }
    }
    denom = fmaxf(denom, 1e-12f);
    out[(size_t)row * EE + lane] = chosen ? (score / denom) : 0.0f;
    out[(size_t)nrows * EE + (size_t)row * EE + lane] = chosen ? 1.0f : 0.0f;
  }
}

// ---------------------------------------------------------------------------
extern "C" void kernel_launch(void* const* d_in, const int* in_sizes, int n_in,
                              void* d_out, int out_size, void* d_ws,
                              size_t ws_size, hipStream_t stream) {
  const float* hidden = (const float*)d_in[0];
  const float* gate_w = (const float*)d_in[1];
  const float* bias = (const float*)d_in[2];
  float* out = (float*)d_out;
  char* ws = (char*)d_ws;

  const int nrows = in_sizes[0] / DD;  // 16384

  size_t tail = (ws_size - 65536) & ~(size_t)255;
  int* counter = (int*)(ws + tail);
  int* list = counter + 1;
  float* part = (float*)ws;                          // 16 MiB (ksplit=4)
  float* part2 = (float*)(ws + (size_t)32 * 1024 * 1024);  // 64 MiB max
  const size_t per = (size_t)nrows * EE * sizeof(float);
  const int ksplit = (tail >= 4 * per) ? 4 : 2;

  hipMemsetAsync(counter, 0, sizeof(int), stream);

  dim3 block(256);
  if (ksplit == 4)
    gemm_mfma<4><<<dim3(nrows / 128, 4), block, 0, stream>>>(hidden, gate_w,
                                                             part, nrows);
  else
    gemm_mfma<2><<<dim3(nrows / 128, 2), block, 0, stream>>>(hidden, gate_w,
                                                             part, nrows);
  topk_kernel<<<dim3(nrows / 4), block, 0, stream>>>(part, bias, out, nrows,
                                                     ksplit, counter, list);
  fixup_partial<<<dim3(2048), block, 0, stream>>>(hidden, gate_w, counter,
                                                  list, part2);
  fixup_apply<<<dim3(512), block, 0, stream>>>(part2, bias, counter, list, out,
                                               nrows);
}

// Round 7
// 130.132 us; speedup vs baseline: 1.2593x; 1.0736x over previous
//
#include <hip/hip_runtime.h>
#include <math.h>

#define DD 4096
#define EE 64
#define BK 32
#define TAU 1e-4f
#define NEG_SENTINEL -1.0e30f
#define MAXFIX 16000

typedef __attribute__((ext_vector_type(8))) short short8v;
typedef __attribute__((ext_vector_type(4))) float f32x4;

union BF8 {
  uint4 u;
  short8v s;
};

__device__ __forceinline__ unsigned asu(float f) {
  union { float f; unsigned u; } v; v.f = f; return v.u;
}
__device__ __forceinline__ float asf(unsigned u) {
  union { unsigned u; float f; } v; v.u = u; return v.f;
}

// Split 8 f32 into hi/lo bf16 (RNE both): x = hi + lo + O(2^-17 |x|).
__device__ __forceinline__ void split8(const float x[8], uint4& hi, uint4& lo) {
  unsigned h[8], l[8];
#pragma unroll
  for (int j = 0; j < 8; j++) {
    unsigned u = asu(x[j]);
    unsigned r = (u + 0x7fffu + ((u >> 16) & 1u)) & 0xffff0000u;
    h[j] = r;
    unsigned v = asu(x[j] - asf(r));
    l[j] = (v + 0x7fffu + ((v >> 16) & 1u)) & 0xffff0000u;
  }
  hi = make_uint4((h[0] >> 16) | h[1], (h[2] >> 16) | h[3],
                  (h[4] >> 16) | h[5], (h[6] >> 16) | h[7]);
  lo = make_uint4((l[0] >> 16) | l[1], (l[2] >> 16) | l[3],
                  (l[4] >> 16) | l[5], (l[6] >> 16) | l[7]);
}

// ---------------------------------------------------------------------------
// Kernel 1: bf16-split MFMA partial GEMM, A direct-to-register (no A LDS).
// R7 changes vs R5/R6 (hypothesis: stall-bound at 2 waves/SIMD):
//   - ksplit 8 -> grid 1024 = 4 blocks/CU = 4 waves/SIMD (16 KB LDS x4 = 64KB)
//   - __launch_bounds__(256,4): cap VGPR at 128 for 4 waves/SIMD
//   - MFMA issue reordered pass-outer: consecutive MFMAs never share an acc
//     (per-acc op order unchanged -> bitwise-identical results)
// ---------------------------------------------------------------------------
template <int KSPLIT>
__global__ __launch_bounds__(256, 4) void gemm_mfma(
    const float* __restrict__ hidden, const float* __restrict__ gate_w,
    float* __restrict__ part, int nrows) {
  __shared__ __align__(16) char smem[16384];

  const int tid = threadIdx.x;
  const int lane = tid & 63;
  const int wv = tid >> 6;
  const int fr = lane & 15;
  const int fg = lane >> 4;
  const int m0 = blockIdx.x * 128;
  const int kslice = DD / KSPLIT;
  const int nsteps = kslice / BK;
  const int k0 = blockIdx.y * kslice;

  const float* pA0 = hidden + (size_t)(m0 + wv * 32 + fr) * DD + k0 + fg * 8;
  const float* pA1 = pA0 + (size_t)16 * DD;
  const int be = tid & 63;
  const int bs = tid >> 6;
  const float* pB = gate_w + (size_t)be * DD + k0 + bs * 8;
  const int wline = be >> 1;
  const int woff = wline * 128 + ((((be & 1) << 2) | bs) ^ (wline & 7)) * 16;
  const int rbase =
      (fr >> 1) * 128 + ((((fr & 1) << 2) | fg) ^ ((fr >> 1) & 7)) * 16;

  float4 ac[2][2], an[2][2], bn[2];

  auto stageB = [&](int nb) {
    float xb[8] = {bn[0].x, bn[0].y, bn[0].z, bn[0].w,
                   bn[1].x, bn[1].y, bn[1].z, bn[1].w};
    uint4 hi, lo;
    split8(xb, hi, lo);
    *(uint4*)(smem + nb + woff) = hi;
    *(uint4*)(smem + nb + 4096 + woff) = lo;
  };

  ac[0][0] = *(const float4*)pA0;
  ac[0][1] = *(const float4*)(pA0 + 4);
  ac[1][0] = *(const float4*)pA1;
  ac[1][1] = *(const float4*)(pA1 + 4);
  bn[0] = *(const float4*)pB;
  bn[1] = *(const float4*)(pB + 4);
  pA0 += BK; pA1 += BK; pB += BK;
  stageB(0);
  an[0][0] = *(const float4*)pA0;
  an[0][1] = *(const float4*)(pA0 + 4);
  an[1][0] = *(const float4*)pA1;
  an[1][1] = *(const float4*)(pA1 + 4);
  bn[0] = *(const float4*)pB;
  bn[1] = *(const float4*)(pB + 4);
  pA0 += BK; pA1 += BK; pB += BK;
  asm volatile("s_waitcnt lgkmcnt(0)" ::: "memory");
  __builtin_amdgcn_s_barrier();
  asm volatile("" ::: "memory");

  f32x4 zero4 = {0.f, 0.f, 0.f, 0.f};
  f32x4 acc[2][4];
#pragma unroll
  for (int mt = 0; mt < 2; mt++)
#pragma unroll
    for (int nt = 0; nt < 4; nt++) acc[mt][nt] = zero4;

  for (int t = 0; t < nsteps; t++) {
    const int cb = (t & 1) << 13;
    BF8 ah[2], al[2];
#pragma unroll
    for (int mt = 0; mt < 2; mt++) {
      float xa[8] = {ac[mt][0].x, ac[mt][0].y, ac[mt][0].z, ac[mt][0].w,
                     ac[mt][1].x, ac[mt][1].y, ac[mt][1].z, ac[mt][1].w};
      split8(xa, ah[mt].u, al[mt].u);
    }
    if (t + 1 < nsteps) stageB(cb ^ 8192);
#pragma unroll
    for (int mt = 0; mt < 2; mt++) {
      ac[mt][0] = an[mt][0];
      ac[mt][1] = an[mt][1];
    }
    if (t + 2 < nsteps) {
      an[0][0] = *(const float4*)pA0;
      an[0][1] = *(const float4*)(pA0 + 4);
      an[1][0] = *(const float4*)pA1;
      an[1][1] = *(const float4*)(pA1 + 4);
      bn[0] = *(const float4*)pB;
      bn[1] = *(const float4*)(pB + 4);
      pA0 += BK; pA1 += BK; pB += BK;
    }
    // hoist all B-frag reads, then 3 passes with no back-to-back acc reuse
    BF8 bh[4], bl[4];
#pragma unroll
    for (int nt = 0; nt < 4; nt++) {
      bh[nt].u = *(const uint4*)(smem + cb + rbase + nt * 1024);
      bl[nt].u = *(const uint4*)(smem + cb + 4096 + rbase + nt * 1024);
    }
#pragma unroll
    for (int nt = 0; nt < 4; nt++)
#pragma unroll
      for (int mt = 0; mt < 2; mt++)
        acc[mt][nt] = __builtin_amdgcn_mfma_f32_16x16x32_bf16(
            ah[mt].s, bh[nt].s, acc[mt][nt], 0, 0, 0);
#pragma unroll
    for (int nt = 0; nt < 4; nt++)
#pragma unroll
      for (int mt = 0; mt < 2; mt++)
        acc[mt][nt] = __builtin_amdgcn_mfma_f32_16x16x32_bf16(
            ah[mt].s, bl[nt].s, acc[mt][nt], 0, 0, 0);
#pragma unroll
    for (int nt = 0; nt < 4; nt++)
#pragma unroll
      for (int mt = 0; mt < 2; mt++)
        acc[mt][nt] = __builtin_amdgcn_mfma_f32_16x16x32_bf16(
            al[mt].s, bh[nt].s, acc[mt][nt], 0, 0, 0);
    asm volatile("s_waitcnt lgkmcnt(0)" ::: "memory");
    __builtin_amdgcn_s_barrier();
    asm volatile("" ::: "memory");
  }

  float* dst = part + (size_t)blockIdx.y * nrows * EE;
#pragma unroll
  for (int mt = 0; mt < 2; mt++)
#pragma unroll
    for (int j = 0; j < 4; j++) {
      const int r = m0 + wv * 32 + mt * 16 + fg * 4 + j;
#pragma unroll
      for (int nt = 0; nt < 4; nt++)
        dst[(size_t)r * EE + nt * 16 + fr] = acc[mt][nt][j];
    }
}

// ---------------------------------------------------------------------------
// Kernel 2: reduce partials, sqrt(softplus), top-8, renormalize, scatter.
// Flags rows with selection margin < TAU for exact f32 recompute.
// ---------------------------------------------------------------------------
__global__ __launch_bounds__(256) void topk_kernel(
    const float* __restrict__ part, const float* __restrict__ bias,
    float* __restrict__ out, int nrows, int ksplit, int* __restrict__ counter,
    int* __restrict__ list) {
  const int lane = threadIdx.x & 63;
  const int row = blockIdx.x * 4 + (threadIdx.x >> 6);

  float logit = 0.0f;
  for (int s = 0; s < ksplit; s++)
    logit += part[(size_t)s * nrows * EE + (size_t)row * EE + lane];

  float sp = (logit > 0.0f) ? (logit + log1pf(expf(-logit)))
                            : log1pf(expf(logit));
  float score = sqrtf(sp);
  float sel = score + bias[lane];

  float denom = 0.0f, v8 = 0.0f;
  bool chosen = false;
#pragma unroll
  for (int t = 0; t < 8; t++) {
    float v = sel;
    int idx = lane;
#pragma unroll
    for (int m = 1; m < 64; m <<= 1) {
      float ov = __shfl_xor(v, m, 64);
      int oi = __shfl_xor(idx, m, 64);
      if (ov > v || (ov == v && oi < idx)) { v = ov; idx = oi; }
    }
    float wscore = __shfl(score, idx, 64);
    denom += wscore;
    v8 = v;
    if (lane == idx) { chosen = true; sel = NEG_SENTINEL; }
  }
  float v9 = sel;
#pragma unroll
  for (int m = 1; m < 64; m <<= 1) v9 = fmaxf(v9, __shfl_xor(v9, m, 64));
  if (lane == 0 && (v8 - v9) < TAU) {
    int ix = atomicAdd(counter, 1);
    if (ix < MAXFIX) list[ix] = row;
  }

  denom = fmaxf(denom, 1e-12f);
  out[(size_t)row * EE + lane] = chosen ? (score / denom) : 0.0f;
  out[(size_t)nrows * EE + (size_t)row * EE + lane] = chosen ? 1.0f : 0.0f;
}

// ---------------------------------------------------------------------------
// Kernel 3a: exact-f32 partial dots for flagged rows, k-split 16 ways.
// ---------------------------------------------------------------------------
__global__ __launch_bounds__(256) void fixup_partial(
    const float* __restrict__ hidden, const float* __restrict__ gate_w,
    const int* __restrict__ counter, const int* __restrict__ list,
    float* __restrict__ part2) {
  __shared__ float red[EE][4];
  int cnt = *counter;
  if (cnt > MAXFIX) cnt = MAXFIX;
  const int total = cnt * 16;
  const int e = threadIdx.x & 63;
  const int q = threadIdx.x >> 6;
  for (int w = blockIdx.x; w < total; w += gridDim.x) {
    const int i = w >> 4;
    const int c = w & 15;
    const int row = list[i];
    const int kb = c * 256 + q * 64;
    const float* hp = hidden + (size_t)row * DD + kb;
    const float* wp = gate_w + (size_t)e * DD + kb;
    float s = 0.f;
#pragma unroll
    for (int k = 0; k < 64; k += 4) {
      float4 a = *(const float4*)(hp + k);
      float4 b = *(const float4*)(wp + k);
      s = fmaf(a.w, b.w, fmaf(a.z, b.z, fmaf(a.y, b.y, fmaf(a.x, b.x, s))));
    }
    red[e][q] = s;
    __syncthreads();
    if (threadIdx.x < EE)
      part2[(size_t)i * 1024 + threadIdx.x * 16 + c] =
          (red[threadIdx.x][0] + red[threadIdx.x][1]) +
          (red[threadIdx.x][2] + red[threadIdx.x][3]);
    __syncthreads();
  }
}

// ---------------------------------------------------------------------------
// Kernel 3b: sum the 16 chunks in fixed order, redo top-8 exactly, rewrite.
// ---------------------------------------------------------------------------
__global__ __launch_bounds__(256) void fixup_apply(
    const float* __restrict__ part2, const float* __restrict__ bias,
    const int* __restrict__ counter, const int* __restrict__ list,
    float* __restrict__ out, int nrows) {
  int cnt = *counter;
  if (cnt > MAXFIX) cnt = MAXFIX;
  const int lane = threadIdx.x & 63;
  const int wv = threadIdx.x >> 6;
  for (int i0 = blockIdx.x * 4; i0 < cnt; i0 += gridDim.x * 4) {
    const int i = i0 + wv;
    if (i >= cnt) continue;
    const int row = list[i];
    const float* pp = part2 + (size_t)i * 1024 + lane * 16;
    float logit = 0.f;
#pragma unroll
    for (int c = 0; c < 16; c++) logit += pp[c];

    float sp = (logit > 0.0f) ? (logit + log1pf(expf(-logit)))
                              : log1pf(expf(logit));
    float score = sqrtf(sp);
    float sel = score + bias[lane];
    float denom = 0.0f;
    bool chosen = false;
#pragma unroll
    for (int t = 0; t < 8; t++) {
      float v = sel;
      int idx = lane;
#pragma unroll
      for (int m = 1; m < 64; m <<= 1) {
        float ov = __shfl_xor(v, m, 64);
        int oi = __shfl_xor(idx, m, 64);
        if (ov > v || (ov == v && oi < idx)) { v = ov; idx = oi; }
      }
      float wscore = __shfl(score, idx, 64);
      denom += wscore;
      if (lane == idx) { chosen = true; sel = NEG_SENTINEL; }
    }
    denom = fmaxf(denom, 1e-12f);
    out[(size_t)row * EE + lane] = chosen ? (score / denom) : 0.0f;
    out[(size_t)nrows * EE + (size_t)row * EE + lane] = chosen ? 1.0f : 0.0f;
  }
}

// ---------------------------------------------------------------------------
extern "C" void kernel_launch(void* const* d_in, const int* in_sizes, int n_in,
                              void* d_out, int out_size, void* d_ws,
                              size_t ws_size, hipStream_t stream) {
  const float* hidden = (const float*)d_in[0];
  const float* gate_w = (const float*)d_in[1];
  const float* bias = (const float*)d_in[2];
  float* out = (float*)d_out;
  char* ws = (char*)d_ws;

  const int nrows = in_sizes[0] / DD;  // 16384

  size_t tail = (ws_size - 65536) & ~(size_t)255;
  int* counter = (int*)(ws + tail);
  int* list = counter + 1;
  float* part = (float*)ws;                                // up to 32 MiB
  float* part2 = (float*)(ws + (size_t)64 * 1024 * 1024);  // 64 MiB max
  const size_t per = (size_t)nrows * EE * sizeof(float);   // 4 MiB
  const int ksplit = (tail >= 8 * per) ? 8 : 4;

  hipMemsetAsync(counter, 0, sizeof(int), stream);

  dim3 block(256);
  if (ksplit == 8)
    gemm_mfma<8><<<dim3(nrows / 128, 8), block, 0, stream>>>(hidden, gate_w,
                                                             part, nrows);
  else
    gemm_mfma<4><<<dim3(nrows / 128, 4), block, 0, stream>>>(hidden, gate_w,
                                                             part, nrows);
  topk_kernel<<<dim3(nrows / 4), block, 0, stream>>>(part, bias, out, nrows,
                                                     ksplit, counter, list);
  fixup_partial<<<dim3(2048), block, 0, stream>>>(hidden, gate_w, counter,
                                                  list, part2);
  fixup_apply<<<dim3(512), block, 0, stream>>>(part2, bias, counter, list, out,
                                               nrows);
}